// Round 8
// baseline (54285.699 us; speedup 1.0000x reference)
//
#include <hip/hip_runtime.h>
#include <cfloat>

// Problem constants (fixed by setup_inputs)
#define BATCH 128
#define NP    16384
#define NC    4096
#define MPTS  (NP + NC)   // 20480
#define SOUT  2048

// Pair-split config: 2 blocks per batch, 512 threads each, 20 pts/thread.
#define NTHR2 512
#define KPT2  20
#define HALFP (MPTS / 2)   // 10240 points per half-block

// Fallback (round-6 proven) config: 1 block per batch, 1024 threads.
#define NTHR1 1024
#define KPT1  20

// One DPP max-reduce step on a u64 key split across (hi, lo) u32 regs.
// old=0 / bound_ctrl=false: invalid-source lanes contribute key 0, which is
// the identity for our max (all real keys are > 0). Proven bit-exact in r6/r7.
#define DPP_MAX_STEP(ctrl, rmask)                                                  \
    {                                                                              \
        unsigned int lo2 = (unsigned int)__builtin_amdgcn_update_dpp(              \
            0, (int)klo, (ctrl), (rmask), 0xF, false);                             \
        unsigned int hi2 = (unsigned int)__builtin_amdgcn_update_dpp(              \
            0, (int)khi, (ctrl), (rmask), 0xF, false);                             \
        const unsigned long long a =                                               \
            ((unsigned long long)khi << 32) | (unsigned long long)klo;             \
        const unsigned long long c =                                               \
            ((unsigned long long)hi2 << 32) | (unsigned long long)lo2;             \
        if (c > a) { klo = lo2; khi = hi2; }                                       \
    }

#define WAVE_MAX_REDUCE()                                                          \
    DPP_MAX_STEP(0x111, 0xF)  /* row_shr:1  */                                     \
    DPP_MAX_STEP(0x112, 0xF)  /* row_shr:2  */                                     \
    DPP_MAX_STEP(0x114, 0xF)  /* row_shr:4  */                                     \
    DPP_MAX_STEP(0x118, 0xF)  /* row_shr:8  */                                     \
    DPP_MAX_STEP(0x142, 0xa)  /* row_bcast:15 */                                   \
    DPP_MAX_STEP(0x143, 0xc)  /* row_bcast:31 */

// Reference-exact distance (proven bit-exact rounds 3/6/7):
// fma(dz,dz, fma(dx,dx, rn(dy*dy)))
__device__ __forceinline__ float ref_dist(float px, float py, float pz,
                                          float qx, float qy, float qz) {
    const float dx = __fsub_rn(px, qx);
    const float dy = __fsub_rn(py, qy);
    const float dz = __fsub_rn(pz, qz);
    const float dy2 = __fmul_rn(dy, dy);
    return __builtin_fmaf(dz, dz, __builtin_fmaf(dx, dx, dy2));
}

// ---------------------------------------------------------------------------
// Pair-split kernel: 256 blocks (= CU count), block pair (2b, 2b+1) shares
// batch b. Each block owns HALFP points in registers. Per step: local DPP +
// LDS argmax reduce (one barrier), then the pair exchanges winner keys via a
// per-(batch,step) slot in d_ws. Slots are written exactly once per launch;
// the harness's 0xAA pre-poison (top bit set) is the "not ready" sentinel —
// real keys have top bit 0 because distances are >= 0. Release/acquire
// agent-scope atomics make the handshake safe across XCDs.
// ---------------------------------------------------------------------------
__global__ __launch_bounds__(NTHR2)
__attribute__((amdgpu_waves_per_eu(2, 2)))
void fps_pair_kernel(
    const float* __restrict__ partial,       // [B, NP, 3]
    const float* __restrict__ coarse,        // [B, 3, NC]
    float* __restrict__ out,                 // [B, 3, SOUT]
    unsigned long long* __restrict__ slots)  // [B][SOUT][2]
{
    const int bx = blockIdx.x;
    const int b = bx >> 1;
    const int half = bx & 1;
    const int t = threadIdx.x;
    const int wid = t >> 6;
    const int lane = t & 63;
    const int mbase = half * HALFP;          // global index of my first point

    __shared__ unsigned long long s_keys[8]; // per-wave argmax candidates

    float x[KPT2], y[KPT2], z[KPT2], md[KPT2];

    const float* Pb = partial + (size_t)b * NP * 3;
    const float* Cb = coarse + (size_t)b * 3 * NC;
    unsigned long long* slot_b = slots + (size_t)b * SOUT * 2;

#pragma unroll
    for (int k = 0; k < KPT2; ++k) {
        const int m = mbase + k * NTHR2 + t;   // global point index
        if (m < NP) {      // from partial ([M,3] layout)
            x[k] = Pb[(size_t)m * 3 + 0];
            y[k] = Pb[(size_t)m * 3 + 1];
            z[k] = Pb[(size_t)m * 3 + 2];
        } else {           // from coarse ([3,NC] layout)
            const int j = m - NP;
            x[k] = Cb[0 * NC + j];
            y[k] = Cb[1 * NC + j];
            z[k] = Cb[2 * NC + j];
        }
        md[k] = FLT_MAX;
    }

    float* outb = out + (size_t)b * 3 * SOUT;

    // First selected index is 0: uniform read of its coords.
    float qx = Pb[0], qy = Pb[1], qz = Pb[2];
    if (half == 0 && t == 0) {
        outb[0 * SOUT + 0] = qx;
        outb[1 * SOUT + 0] = qy;
        outb[2 * SOUT + 0] = qz;
    }

    for (int s = 0; s < SOUT - 1; ++s) {
        float bv = -1.0f;
        int bi = 0;
#pragma unroll
        for (int k = 0; k < KPT2; ++k) {
            const float d = ref_dist(x[k], y[k], z[k], qx, qy, qz);
            const float nmd = fminf(md[k], d);
            md[k] = nmd;
            // Strict > with ascending k keeps the earliest index on ties.
            if (nmd > bv) { bv = nmd; bi = k; }
        }

        // Pack (value, ~m_global): float bits monotone for v>=0; ~m resolves
        // equal values to the smallest GLOBAL index, order-independently.
        const unsigned int mg = (unsigned int)(mbase + (bi << 9) + t);
        unsigned int klo = ~mg;
        unsigned int khi = __float_as_uint(bv);

        WAVE_MAX_REDUCE()

        if (lane == 63) {
            s_keys[wid] = ((unsigned long long)khi << 32) | (unsigned long long)klo;
        }
        __syncthreads();

        // Block-local max of the 8 wave candidates (redundant on all threads).
        unsigned long long lk = s_keys[0];
#pragma unroll
        for (int w = 1; w < 8; ++w) {
            const unsigned long long c = s_keys[w];
            if (c > lk) lk = c;
        }

        // Publish my half's key; spin for the partner's.
        if (t == 0) {
            __hip_atomic_store(&slot_b[2 * s + half], lk,
                               __ATOMIC_RELEASE, __HIP_MEMORY_SCOPE_AGENT);
        }
        unsigned long long pk;
        do {
            pk = __hip_atomic_load(&slot_b[2 * s + (half ^ 1)],
                                   __ATOMIC_ACQUIRE, __HIP_MEMORY_SCOPE_AGENT);
        } while (pk >> 63);   // 0xAA poison has top bit set; real keys don't

        const unsigned long long wk = (pk > lk) ? pk : lk;
        const unsigned int m = ~((unsigned int)wk);   // global winner index

        // Reload winner coords (uniform address -> broadcast; bit-exact).
        const int j = (int)m - NP;
        if (m < NP) {
            qx = Pb[(size_t)m * 3 + 0];
            qy = Pb[(size_t)m * 3 + 1];
            qz = Pb[(size_t)m * 3 + 2];
        } else {
            qx = Cb[0 * NC + j];
            qy = Cb[1 * NC + j];
            qz = Cb[2 * NC + j];
        }

        if (half == 0 && t == 0) {
            const int slot = s + 1;
            outb[0 * SOUT + slot] = qx;
            outb[1 * SOUT + slot] = qy;
            outb[2 * SOUT + slot] = qz;
        }
        // s_keys WAR across steps is safe without a second barrier: the next
        // write to s_keys happens only after a wave finishes the ~20-point
        // distance loop, long after all waves read s_keys above.
    }
}

// ---------------------------------------------------------------------------
// Fallback: round-6 proven single-block-per-batch kernel (3554 us).
// Used only if ws_size can't hold the handshake slots.
// ---------------------------------------------------------------------------
__global__ __launch_bounds__(NTHR1)
__attribute__((amdgpu_waves_per_eu(4, 4)))
void fps_single_kernel(
    const float* __restrict__ partial,
    const float* __restrict__ coarse,
    float* __restrict__ out)
{
    const int b = blockIdx.x;
    const int t = threadIdx.x;
    const int lane = t & 63;

    __shared__ float s_q[4];
    __shared__ unsigned long long s_key[2];

    float x[KPT1], y[KPT1], z[KPT1], md[KPT1];

    const float* Pb = partial + (size_t)b * NP * 3;
    const float* Cb = coarse + (size_t)b * 3 * NC;

#pragma unroll
    for (int k = 0; k < KPT1; ++k) {
        const int m = k * NTHR1 + t;
        if (k < 16) {
            x[k] = Pb[m * 3 + 0]; y[k] = Pb[m * 3 + 1]; z[k] = Pb[m * 3 + 2];
        } else {
            const int j = m - NP;
            x[k] = Cb[0 * NC + j]; y[k] = Cb[1 * NC + j]; z[k] = Cb[2 * NC + j];
        }
        md[k] = FLT_MAX;
    }

    float* outb = out + (size_t)b * 3 * SOUT;
    if (t == 0) {
        s_q[0] = x[0]; s_q[1] = y[0]; s_q[2] = z[0];
        outb[0 * SOUT + 0] = x[0];
        outb[1 * SOUT + 0] = y[0];
        outb[2 * SOUT + 0] = z[0];
        s_key[0] = 0ULL; s_key[1] = 0ULL;
    }
    __syncthreads();

    float qx = s_q[0], qy = s_q[1], qz = s_q[2];

    for (int s = 0; s < SOUT - 1; ++s) {
        const int cur = s & 1, nxt = cur ^ 1;
        float bv = -1.0f;
        int bi = 0;
#pragma unroll
        for (int k = 0; k < KPT1; ++k) {
            const float d = ref_dist(x[k], y[k], z[k], qx, qy, qz);
            const float nmd = fminf(md[k], d);
            md[k] = nmd;
            if (nmd > bv) { bv = nmd; bi = k; }
        }
        unsigned int klo = ~((unsigned int)((bi << 10) | t));
        unsigned int khi = __float_as_uint(bv);
        WAVE_MAX_REDUCE()
        if (lane == 63) {
            atomicMax(&s_key[cur],
                      ((unsigned long long)khi << 32) | (unsigned long long)klo);
        }
        if (t == 0) s_key[nxt] = 0ULL;
        __syncthreads();

        const unsigned long long wk = s_key[cur];
        const unsigned int mid = ~((unsigned int)(wk & 0xFFFFFFFFULL));
        if ((mid & (NTHR1 - 1)) == (unsigned int)t) {
            const int kk = (int)(mid >> 10);
            float wx = 0.f, wy = 0.f, wz = 0.f;
#pragma unroll
            for (int k = 0; k < KPT1; ++k) {
                if (k == kk) { wx = x[k]; wy = y[k]; wz = z[k]; }
            }
            s_q[0] = wx; s_q[1] = wy; s_q[2] = wz;
            const int slot = s + 1;
            outb[0 * SOUT + slot] = wx;
            outb[1 * SOUT + slot] = wy;
            outb[2 * SOUT + slot] = wz;
        }
        __syncthreads();
        qx = s_q[0]; qy = s_q[1]; qz = s_q[2];
    }
}

extern "C" void kernel_launch(void* const* d_in, const int* in_sizes, int n_in,
                              void* d_out, int out_size, void* d_ws, size_t ws_size,
                              hipStream_t stream) {
    (void)in_sizes; (void)n_in; (void)out_size;
    const float* partial = (const float*)d_in[0];
    const float* coarse  = (const float*)d_in[1];
    float* out = (float*)d_out;

    const size_t need = (size_t)BATCH * SOUT * 2 * sizeof(unsigned long long);
    if (ws_size >= need) {
        unsigned long long* slots = (unsigned long long*)d_ws;
        void* args[] = {(void*)&partial, (void*)&coarse, (void*)&out, (void*)&slots};
        // Cooperative launch guarantees all 256 blocks (= CU count) co-resident,
        // so the pairwise spin handshake cannot deadlock.
        hipError_t e = hipLaunchCooperativeKernel((void*)fps_pair_kernel,
                                                  dim3(2 * BATCH), dim3(NTHR2),
                                                  args, 0, stream);
        if (e == hipSuccess) return;
        // Fallback: plain launch. Grid == CU count with <=8 waves + 64B LDS per
        // block -> all blocks resident on an idle GPU; handshake still safe.
        fps_pair_kernel<<<dim3(2 * BATCH), dim3(NTHR2), 0, stream>>>(
            partial, coarse, out, (unsigned long long*)d_ws);
        return;
    }
    // ws too small for handshake slots: proven single-block-per-batch kernel.
    fps_single_kernel<<<dim3(BATCH), dim3(NTHR1), 0, stream>>>(partial, coarse, out);
}

// Round 9
// 3308.678 us; speedup vs baseline: 16.4071x; 16.4071x over previous
//
#include <hip/hip_runtime.h>
#include <cfloat>

// Problem constants (fixed by setup_inputs)
#define BATCH 128
#define NP    16384
#define NC    4096
#define MPTS  (NP + NC)   // 20480
#define SOUT  2048
#define NTHR  1024
#define KPT   20          // points per thread, CONTIGUOUS: m = t*KPT + k
#define NWAVE (NTHR / 64)

// One f32 DPP max step. old=0 / bound_ctrl=false: lanes with invalid source
// (or masked rows) contribute 0.0f, the identity for max over md >= 0.
#define DPP_MAXF_STEP(ctrl, rmask)                                                 \
    {                                                                              \
        const unsigned int o = (unsigned int)__builtin_amdgcn_update_dpp(          \
            0, (int)__float_as_uint(wv), (ctrl), (rmask), 0xF, false);             \
        wv = fmaxf(wv, __uint_as_float(o));                                        \
    }

// Reference-exact distance (proven bit-exact rounds 3/6/7):
// fma(dz,dz, fma(dx,dx, rn(dy*dy)))
__device__ __forceinline__ float ref_dist(float px, float py, float pz,
                                          float qx, float qy, float qz) {
    const float dx = __fsub_rn(px, qx);
    const float dy = __fsub_rn(py, qy);
    const float dz = __fsub_rn(pz, qz);
    const float dy2 = __fmul_rn(dy, dy);
    return __builtin_fmaf(dz, dz, __builtin_fmaf(dx, dx, dy2));
}

// One block per batch (128 blocks, 16 waves). Each thread owns 20 CONTIGUOUS
// points m = t*20+k in registers. Per step:
//   phase A: distance+min update, value-only running max (v_max3-fusable),
//            6-step f32 DPP wave max, lane63 -> s_val[wid], barrier;
//   phase B: all threads max 16 broadcast floats -> bvmax; candidate threads
//            (bv==bvmax, ~1 wave) scan their 20 md for the first k and
//            atomicMin the GLOBAL index (exact first-index tie semantics,
//            since contiguous ownership makes (t,k) order == m order);
//            barrier; winner coords reloaded from global at a uniform,
//            L2-resident address (bit-exact same data; no third barrier,
//            no divergent 20-deep register select).
__global__ __launch_bounds__(NTHR)
__attribute__((amdgpu_waves_per_eu(4, 4)))
void fps_kernel(
    const float* __restrict__ partial,   // [B, NP, 3]
    const float* __restrict__ coarse,    // [B, 3, NC]
    float* __restrict__ out)             // [B, 3, SOUT]
{
    const int b = blockIdx.x;
    const int t = threadIdx.x;
    const int wid = t >> 6;
    const int lane = t & 63;

    __shared__ __align__(16) float s_val[NWAVE];  // per-wave max values
    __shared__ unsigned int s_mi[2];              // double-buffered argmin-index

    float x[KPT], y[KPT], z[KPT], md[KPT];

    const float* Pb = partial + (size_t)b * NP * 3;
    const float* Cb = coarse + (size_t)b * 3 * NC;

#pragma unroll
    for (int k = 0; k < KPT; ++k) {
        const int m = t * KPT + k;      // contiguous ownership
        if (m < NP) {                   // from partial ([M,3] layout)
            x[k] = Pb[(size_t)m * 3 + 0];
            y[k] = Pb[(size_t)m * 3 + 1];
            z[k] = Pb[(size_t)m * 3 + 2];
        } else {                        // from coarse ([3,NC] layout)
            const int j = m - NP;
            x[k] = Cb[0 * NC + j];
            y[k] = Cb[1 * NC + j];
            z[k] = Cb[2 * NC + j];
        }
        md[k] = FLT_MAX;
    }

    float* outb = out + (size_t)b * 3 * SOUT;

    // First selected index is 0: uniform read of its coords (L2-resident).
    float qx = Pb[0], qy = Pb[1], qz = Pb[2];
    if (t == 0) {
        outb[0 * SOUT + 0] = qx;
        outb[1 * SOUT + 0] = qy;
        outb[2 * SOUT + 0] = qz;
        s_mi[0] = 0xFFFFFFFFu;
        s_mi[1] = 0xFFFFFFFFu;
    }
    __syncthreads();

    for (int s = 0; s < SOUT - 1; ++s) {
        const int cur = s & 1, nxt = cur ^ 1;

        // ---- phase A: update min-distances, track max VALUE only ----
        float bv = 0.0f;   // md >= 0 always, so 0 is a safe identity
#pragma unroll
        for (int kp = 0; kp < KPT; kp += 2) {
            const float d0 = ref_dist(x[kp], y[kp], z[kp], qx, qy, qz);
            const float n0 = fminf(md[kp], d0);
            md[kp] = n0;
            const float d1 = ref_dist(x[kp + 1], y[kp + 1], z[kp + 1], qx, qy, qz);
            const float n1 = fminf(md[kp + 1], d1);
            md[kp + 1] = n1;
            bv = fmaxf(fmaxf(bv, n0), n1);   // fuses to v_max3_f32
        }

        // Wave max to lane 63 (canonical gfx9 pattern, f32 this time).
        float wv = bv;
        DPP_MAXF_STEP(0x111, 0xF)  // row_shr:1
        DPP_MAXF_STEP(0x112, 0xF)  // row_shr:2
        DPP_MAXF_STEP(0x114, 0xF)  // row_shr:4
        DPP_MAXF_STEP(0x118, 0xF)  // row_shr:8
        DPP_MAXF_STEP(0x142, 0xa)  // row_bcast:15
        DPP_MAXF_STEP(0x143, 0xc)  // row_bcast:31

        if (lane == 63) s_val[wid] = wv;
        if (t == 0) s_mi[nxt] = 0xFFFFFFFFu;   // reset other slot for step s+1
        __syncthreads();

        // ---- phase B: block max (broadcast reads), index resolution ----
        const float4* sv4 = (const float4*)s_val;
        const float4 v0 = sv4[0], v1 = sv4[1], v2 = sv4[2], v3 = sv4[3];
        float bvmax = fmaxf(fmaxf(fmaxf(v0.x, v0.y), fmaxf(v0.z, v0.w)),
                            fmaxf(fmaxf(v1.x, v1.y), fmaxf(v1.z, v1.w)));
        bvmax = fmaxf(bvmax,
                      fmaxf(fmaxf(fmaxf(v2.x, v2.y), fmaxf(v2.z, v2.w)),
                            fmaxf(fmaxf(v3.x, v3.y), fmaxf(v3.z, v3.w))));

        if (bv == bvmax) {
            // First k with md[k]==bvmax (descending overwrite keeps smallest).
            int kf = 0;
#pragma unroll
            for (int k = KPT - 1; k >= 0; --k) {
                if (md[k] == bvmax) kf = k;
            }
            atomicMin(&s_mi[cur], (unsigned int)(t * KPT + kf));
        }
        __syncthreads();

        const unsigned int m = s_mi[cur];   // global winner index (uniform)

        // Reload winner coords from global: uniform address -> one L2-hot
        // broadcast per wave; bit-exact same values as the owner's registers.
        if (m < NP) {
            const float* p = Pb + (size_t)m * 3;
            qx = p[0]; qy = p[1]; qz = p[2];
        } else {
            const int j = (int)m - NP;
            qx = Cb[0 * NC + j];
            qy = Cb[1 * NC + j];
            qz = Cb[2 * NC + j];
        }

        if (t == 0) {
            const int slot = s + 1;
            outb[0 * SOUT + slot] = qx;
            outb[1 * SOUT + slot] = qy;
            outb[2 * SOUT + slot] = qz;
        }
        // s_val WAR across steps is safe: step s+1's writes happen after
        // this step's B2 barrier; step s's reads happened before it.
    }
}

extern "C" void kernel_launch(void* const* d_in, const int* in_sizes, int n_in,
                              void* d_out, int out_size, void* d_ws, size_t ws_size,
                              hipStream_t stream) {
    (void)in_sizes; (void)n_in; (void)d_ws; (void)ws_size; (void)out_size;
    const float* partial = (const float*)d_in[0];
    const float* coarse  = (const float*)d_in[1];
    float* out = (float*)d_out;
    fps_kernel<<<dim3(BATCH), dim3(NTHR), 0, stream>>>(partial, coarse, out);
}

// Round 10
// 3112.800 us; speedup vs baseline: 17.4395x; 1.0629x over previous
//
#include <hip/hip_runtime.h>
#include <cfloat>

// Problem constants (fixed by setup_inputs)
#define BATCH 128
#define NP    16384
#define NC    4096
#define MPTS  (NP + NC)   // 20480
#define SOUT  2048
#define NTHR  1024
#define KPT   20          // points per thread, CONTIGUOUS: m = t*KPT + k
#define NWAVE (NTHR / 64)

// One f32 DPP max step. old=0 / bound_ctrl=false: lanes with invalid source
// (or masked rows) contribute 0.0f, the identity for max over md >= 0.
#define DPP_MAXF_STEP(ctrl, rmask)                                                 \
    {                                                                              \
        const unsigned int o = (unsigned int)__builtin_amdgcn_update_dpp(          \
            0, (int)__float_as_uint(wv), (ctrl), (rmask), 0xF, false);             \
        wv = fmaxf(wv, __uint_as_float(o));                                        \
    }

// Reference-exact distance (proven bit-exact rounds 3/6/7/9):
// fma(dz,dz, fma(dx,dx, rn(dy*dy)))
__device__ __forceinline__ float ref_dist(float px, float py, float pz,
                                          float qx, float qy, float qz) {
    const float dx = __fsub_rn(px, qx);
    const float dy = __fsub_rn(py, qy);
    const float dz = __fsub_rn(pz, qz);
    const float dy2 = __fmul_rn(dy, dy);
    return __builtin_fmaf(dz, dz, __builtin_fmaf(dx, dx, dy2));
}

// One block per batch (128 blocks, 16 waves). Each thread owns 20 CONTIGUOUS
// points m = t*20+k in registers. Structure identical to round 9; the single
// change is the VGPR pin at the top of each step: round 9's VGPR_Count=52
// (vs ~100 floats of live state) + FETCH_SIZE bump showed the backend was
// AGPR-shuffling or rematerializing the point arrays every step, spending
// ~60-100 VALU ops/step/wave on register plumbing. The empty asm emits no
// instructions but opaquely redefines each value, forcing arch-VGPR
// residency and defeating remat.
__global__ __launch_bounds__(NTHR)
__attribute__((amdgpu_waves_per_eu(4, 4)))
void fps_kernel(
    const float* __restrict__ partial,   // [B, NP, 3]
    const float* __restrict__ coarse,    // [B, 3, NC]
    float* __restrict__ out)             // [B, 3, SOUT]
{
    const int b = blockIdx.x;
    const int t = threadIdx.x;
    const int wid = t >> 6;
    const int lane = t & 63;

    __shared__ __align__(16) float s_val[NWAVE];  // per-wave max values
    __shared__ unsigned int s_mi[2];              // double-buffered argmin-index

    float x[KPT], y[KPT], z[KPT], md[KPT];

    const float* Pb = partial + (size_t)b * NP * 3;
    const float* Cb = coarse + (size_t)b * 3 * NC;

#pragma unroll
    for (int k = 0; k < KPT; ++k) {
        const int m = t * KPT + k;      // contiguous ownership
        if (m < NP) {                   // from partial ([M,3] layout)
            x[k] = Pb[(size_t)m * 3 + 0];
            y[k] = Pb[(size_t)m * 3 + 1];
            z[k] = Pb[(size_t)m * 3 + 2];
        } else {                        // from coarse ([3,NC] layout)
            const int j = m - NP;
            x[k] = Cb[0 * NC + j];
            y[k] = Cb[1 * NC + j];
            z[k] = Cb[2 * NC + j];
        }
        md[k] = FLT_MAX;
    }

    float* outb = out + (size_t)b * 3 * SOUT;

    // First selected index is 0: uniform read of its coords (L2-resident).
    float qx = Pb[0], qy = Pb[1], qz = Pb[2];
    if (t == 0) {
        outb[0 * SOUT + 0] = qx;
        outb[1 * SOUT + 0] = qy;
        outb[2 * SOUT + 0] = qz;
        s_mi[0] = 0xFFFFFFFFu;
        s_mi[1] = 0xFFFFFFFFu;
    }
    __syncthreads();

    for (int s = 0; s < SOUT - 1; ++s) {
        const int cur = s & 1, nxt = cur ^ 1;

        // Pin the per-thread point state into arch VGPRs for this iteration.
        // Emits no instructions; blocks rematerialization / AGPR shuffling.
#pragma unroll
        for (int k = 0; k < KPT; ++k) {
            asm volatile("" : "+v"(x[k]), "+v"(y[k]), "+v"(z[k]), "+v"(md[k]));
        }

        // ---- phase A: update min-distances, track max VALUE only ----
        float bv = 0.0f;   // md >= 0 always, so 0 is a safe identity
#pragma unroll
        for (int kp = 0; kp < KPT; kp += 2) {
            const float d0 = ref_dist(x[kp], y[kp], z[kp], qx, qy, qz);
            const float n0 = fminf(md[kp], d0);
            md[kp] = n0;
            const float d1 = ref_dist(x[kp + 1], y[kp + 1], z[kp + 1], qx, qy, qz);
            const float n1 = fminf(md[kp + 1], d1);
            md[kp + 1] = n1;
            bv = fmaxf(fmaxf(bv, n0), n1);   // fuses to v_max3_f32
        }

        // Wave max to lane 63 (canonical gfx9 pattern, f32).
        float wv = bv;
        DPP_MAXF_STEP(0x111, 0xF)  // row_shr:1
        DPP_MAXF_STEP(0x112, 0xF)  // row_shr:2
        DPP_MAXF_STEP(0x114, 0xF)  // row_shr:4
        DPP_MAXF_STEP(0x118, 0xF)  // row_shr:8
        DPP_MAXF_STEP(0x142, 0xa)  // row_bcast:15
        DPP_MAXF_STEP(0x143, 0xc)  // row_bcast:31

        if (lane == 63) s_val[wid] = wv;
        if (t == 0) s_mi[nxt] = 0xFFFFFFFFu;   // reset other slot for step s+1
        __syncthreads();

        // ---- phase B: block max (broadcast reads), index resolution ----
        const float4* sv4 = (const float4*)s_val;
        const float4 v0 = sv4[0], v1 = sv4[1], v2 = sv4[2], v3 = sv4[3];
        float bvmax = fmaxf(fmaxf(fmaxf(v0.x, v0.y), fmaxf(v0.z, v0.w)),
                            fmaxf(fmaxf(v1.x, v1.y), fmaxf(v1.z, v1.w)));
        bvmax = fmaxf(bvmax,
                      fmaxf(fmaxf(fmaxf(v2.x, v2.y), fmaxf(v2.z, v2.w)),
                            fmaxf(fmaxf(v3.x, v3.y), fmaxf(v3.z, v3.w))));

        if (bv == bvmax) {
            // First k with md[k]==bvmax (descending overwrite keeps smallest).
            int kf = 0;
#pragma unroll
            for (int k = KPT - 1; k >= 0; --k) {
                if (md[k] == bvmax) kf = k;
            }
            atomicMin(&s_mi[cur], (unsigned int)(t * KPT + kf));
        }
        __syncthreads();

        const unsigned int m = s_mi[cur];   // global winner index (uniform)

        // Reload winner coords from global: uniform address -> one L2-hot
        // broadcast per wave; bit-exact same values as the owner's registers.
        if (m < NP) {
            const float* p = Pb + (size_t)m * 3;
            qx = p[0]; qy = p[1]; qz = p[2];
        } else {
            const int j = (int)m - NP;
            qx = Cb[0 * NC + j];
            qy = Cb[1 * NC + j];
            qz = Cb[2 * NC + j];
        }

        if (t == 0) {
            const int slot = s + 1;
            outb[0 * SOUT + slot] = qx;
            outb[1 * SOUT + slot] = qy;
            outb[2 * SOUT + slot] = qz;
        }
        // s_val WAR across steps is safe: step s+1's writes happen after
        // this step's second barrier; step s's reads happened before it.
    }
}

extern "C" void kernel_launch(void* const* d_in, const int* in_sizes, int n_in,
                              void* d_out, int out_size, void* d_ws, size_t ws_size,
                              hipStream_t stream) {
    (void)in_sizes; (void)n_in; (void)d_ws; (void)ws_size; (void)out_size;
    const float* partial = (const float*)d_in[0];
    const float* coarse  = (const float*)d_in[1];
    float* out = (float*)d_out;
    fps_kernel<<<dim3(BATCH), dim3(NTHR), 0, stream>>>(partial, coarse, out);
}